// Round 9
// baseline (149.563 us; speedup 1.0000x reference)
//
#include <hip/hip_runtime.h>

#define B 64
#define S 512
#define D 768
#define E 32
#define N_ENT (B * E)        // 2048
#define MPE 4
#define M (N_ENT * MPE)      // 8192
#define N_TYPES 6
#define P (B * E * (E - 1))  // 63488

#define D4 (D / 4)                     // 192 float4 slots per row
#define LSE_BLOCKS (N_ENT * D4 / 256)  // 1536 (exactly one f32x4/thread)
#define FEAT_SLOTS (P * 3 * D4)        // 36,569,088 float4 slots
#define TYPES_ELEMS (P * N_TYPES)      // 380,928
#define SWEEP_GRID 2048
#define SWEEP_NT (SWEEP_GRID * 256)    // 524,288 threads

typedef float f32x4 __attribute__((ext_vector_type(4)));

__device__ __forceinline__ float lse4(float a, float b, float c, float d) {
    float mx = fmaxf(fmaxf(a, b), fmaxf(c, d));
    return logf(expf(a - mx) + expf(b - mx) + expf(c - mx) + expf(d - mx)) + mx;
}

// ---------------------------------------------------------------------------
// Kernel A — LSE only (unchanged; measured ~3-5us serial prefix).
// R3 lesson: LSE once per entity, never per pair. R5 lesson: no grid-wide
// barrier/fusion. R7 lesson: no XCD partitioning of the sweep (L3 already
// absorbs the duplicate reads; chunking breaks write interleaving).
// ---------------------------------------------------------------------------
__global__ __launch_bounds__(256) void lse_kernel(
    const float* __restrict__ hidden,
    const int* __restrict__ mention_entity,
    const int* __restrict__ mention_pos,
    float* __restrict__ ent) {
    const unsigned idx = blockIdx.x * 256u + threadIdx.x;  // over N_ENT*D4
    const unsigned e = idx / D4;
    const unsigned d4 = idx - e * D4;
    const int doc = mention_entity[e * MPE] / E;
    const float* rowbase = hidden + (size_t)doc * S * D + (size_t)d4 * 4;

    f32x4 x[MPE];
#pragma unroll
    for (int m = 0; m < MPE; ++m) {
        const int pos = mention_pos[e * MPE + m] + 1;
        x[m] = *(const f32x4*)(rowbase + (size_t)pos * D);
    }
    f32x4 o;
    o.x = lse4(x[0].x, x[1].x, x[2].x, x[3].x);
    o.y = lse4(x[0].y, x[1].y, x[2].y, x[3].y);
    o.z = lse4(x[0].z, x[1].z, x[2].z, x[3].z);
    o.w = lse4(x[0].w, x[1].w, x[2].w, x[3].w);
    *(f32x4*)(ent + (size_t)e * D + (size_t)d4 * 4) = o;
}

// ---------------------------------------------------------------------------
// Kernel B — types prologue + THE contiguous sweep (R1/R6 structure, the
// proven 104us base). Single A/B change vs R6: PLAIN stores instead of
// nontemporal — the 6.7 TB/s fill kernel uses plain stores (L2
// write-combining); NT's eviction protection is worth little (doc-window
// working set ~100 KB, L3-refillable). Everything else byte-identical.
// ---------------------------------------------------------------------------
__global__ __launch_bounds__(256) void sweep_kernel(
    const float* __restrict__ hidden,
    const int* __restrict__ pair_head,
    const int* __restrict__ pair_tail,
    const int* __restrict__ pair_doc,
    const int* __restrict__ ent_type,
    const float* __restrict__ ent,
    f32x4* __restrict__ out4,
    float* __restrict__ out_types) {
    const unsigned tid = blockIdx.x * 256u + threadIdx.x;

    // --- types prologue: <=1 element per thread (380,928 < 524,288) ---
    if (tid < (unsigned)TYPES_ELEMS) {
        const unsigned p = tid / N_TYPES;
        const int ty = (int)(tid - p * N_TYPES);
        const int th = ent_type[pair_head[p]];
        const int tt = ent_type[pair_tail[p]];
        out_types[tid] = (float)((ty == th) + (ty == tt));
    }

    // --- the contiguous feature sweep, plain stores ---
    for (unsigned idx = tid; idx < (unsigned)FEAT_SLOTS; idx += (unsigned)SWEEP_NT) {
        const unsigned p = idx / (3 * D4);          // magic mul
        const unsigned rem = idx - p * (3 * D4);
        const unsigned r = rem / D4;                // 0,1,2 (wave-uniform)
        const unsigned d4 = rem - r * D4;

        const f32x4* src;
        if (r == 0) {
            src = (const f32x4*)(hidden + (size_t)pair_doc[p] * (S * D));
        } else {
            const int q = (r == 1) ? pair_head[p] : pair_tail[p];
            src = (const f32x4*)(ent + (size_t)q * D);
        }
        out4[idx] = src[d4];
    }
}

extern "C" void kernel_launch(void* const* d_in, const int* in_sizes, int n_in,
                              void* d_out, int out_size, void* d_ws, size_t ws_size,
                              hipStream_t stream) {
    const float* hidden       = (const float*)d_in[0];
    const int* mention_entity = (const int*)d_in[1];
    const int* mention_pos    = (const int*)d_in[2];
    const int* pair_head      = (const int*)d_in[3];
    const int* pair_tail      = (const int*)d_in[4];
    const int* pair_doc       = (const int*)d_in[5];
    const int* ent_type       = (const int*)d_in[6];

    float* out       = (float*)d_out;
    f32x4* out4      = (f32x4*)out;              // P*3*D floats
    float* out_types = out + (size_t)P * 3 * D;  // P*N_TYPES floats
    float* ent       = (float*)d_ws;             // N_ENT*D floats = 6.3 MB

    lse_kernel<<<LSE_BLOCKS, 256, 0, stream>>>(
        hidden, mention_entity, mention_pos, ent);

    sweep_kernel<<<SWEEP_GRID, 256, 0, stream>>>(
        hidden, pair_head, pair_tail, pair_doc, ent_type, ent,
        out4, out_types);
}

// Round 10
// 103.928 us; speedup vs baseline: 1.4391x; 1.4391x over previous
//
#include <hip/hip_runtime.h>

#define B 64
#define S 512
#define D 768
#define E 32
#define N_ENT (B * E)        // 2048
#define MPE 4
#define M (N_ENT * MPE)      // 8192
#define N_TYPES 6
#define P (B * E * (E - 1))  // 63488

#define D4 (D / 4)                     // 192 float4 slots per row
#define LSE_BLOCKS (N_ENT * D4 / 256)  // 1536 (exactly one f32x4/thread)
#define FEAT_SLOTS (P * 3 * D4)        // 36,569,088 float4 slots
#define TYPES_ELEMS (P * N_TYPES)      // 380,928
#define SWEEP_GRID 2048
#define SWEEP_NT (SWEEP_GRID * 256)    // 524,288 threads

typedef float f32x4 __attribute__((ext_vector_type(4)));

__device__ __forceinline__ float lse4(float a, float b, float c, float d) {
    float mx = fmaxf(fmaxf(a, b), fmaxf(c, d));
    return logf(expf(a - mx) + expf(b - mx) + expf(c - mx) + expf(d - mx)) + mx;
}

// ---------------------------------------------------------------------------
// FINAL STRUCTURE (= R6, the 103.98us optimum). Falsified alternatives:
//  R2  split sweep (write fragmentation, +12us)
//  R3  inline LSE recompute per pair (62x transcendental multiply, +148us)
//  R4  cooperative-launch fusion (launch rejected)
//  R5  manual grid barrier (L2 invalidate storm from device-scope spin, +140us)
//  R7  XCD-chunked sweep (breaks write interleaving, L3 already absorbs
//      duplicate reads, +9.5us)
//  R8  plain stores (L2 write-allocate thrash evicts ent/cls, +45us
//      -> NT stores are load-bearing)
// Kernel A: per-(entity,d4) logsumexp, once per entity (R3 lesson), ~4-5us.
// Kernel B: types prologue + ONE contiguous grid-stride NT-store sweep over
// all P*3*D4 slots; p/r wave-uniform (strides multiples of 64) -> broadcast
// index loads, 1KB-coalesced reads from L2/L3, streaming NT writes at
// ~6.35 TB/s effective HBM (~fill-kernel parity).
// ---------------------------------------------------------------------------
__global__ __launch_bounds__(256) void lse_kernel(
    const float* __restrict__ hidden,
    const int* __restrict__ mention_entity,
    const int* __restrict__ mention_pos,
    float* __restrict__ ent) {
    const unsigned idx = blockIdx.x * 256u + threadIdx.x;  // over N_ENT*D4
    const unsigned e = idx / D4;
    const unsigned d4 = idx - e * D4;
    const int doc = mention_entity[e * MPE] / E;
    const float* rowbase = hidden + (size_t)doc * S * D + (size_t)d4 * 4;

    f32x4 x[MPE];
#pragma unroll
    for (int m = 0; m < MPE; ++m) {
        const int pos = mention_pos[e * MPE + m] + 1;
        x[m] = *(const f32x4*)(rowbase + (size_t)pos * D);
    }
    f32x4 o;
    o.x = lse4(x[0].x, x[1].x, x[2].x, x[3].x);
    o.y = lse4(x[0].y, x[1].y, x[2].y, x[3].y);
    o.z = lse4(x[0].z, x[1].z, x[2].z, x[3].z);
    o.w = lse4(x[0].w, x[1].w, x[2].w, x[3].w);
    *(f32x4*)(ent + (size_t)e * D + (size_t)d4 * 4) = o;
}

__global__ __launch_bounds__(256) void sweep_kernel(
    const float* __restrict__ hidden,
    const int* __restrict__ pair_head,
    const int* __restrict__ pair_tail,
    const int* __restrict__ pair_doc,
    const int* __restrict__ ent_type,
    const float* __restrict__ ent,
    f32x4* __restrict__ out4,
    float* __restrict__ out_types) {
    const unsigned tid = blockIdx.x * 256u + threadIdx.x;

    // --- types prologue: <=1 element per thread (380,928 < 524,288) ---
    if (tid < (unsigned)TYPES_ELEMS) {
        const unsigned p = tid / N_TYPES;
        const int ty = (int)(tid - p * N_TYPES);
        const int th = ent_type[pair_head[p]];
        const int tt = ent_type[pair_tail[p]];
        out_types[tid] = (float)((ty == th) + (ty == tt));
    }

    // --- the contiguous feature sweep (nontemporal stores) ---
    for (unsigned idx = tid; idx < (unsigned)FEAT_SLOTS; idx += (unsigned)SWEEP_NT) {
        const unsigned p = idx / (3 * D4);          // magic mul
        const unsigned rem = idx - p * (3 * D4);
        const unsigned r = rem / D4;                // 0,1,2 (wave-uniform)
        const unsigned d4 = rem - r * D4;

        const f32x4* src;
        if (r == 0) {
            src = (const f32x4*)(hidden + (size_t)pair_doc[p] * (S * D));
        } else {
            const int q = (r == 1) ? pair_head[p] : pair_tail[p];
            src = (const f32x4*)(ent + (size_t)q * D);
        }
        __builtin_nontemporal_store(src[d4], &out4[idx]);
    }
}

extern "C" void kernel_launch(void* const* d_in, const int* in_sizes, int n_in,
                              void* d_out, int out_size, void* d_ws, size_t ws_size,
                              hipStream_t stream) {
    const float* hidden       = (const float*)d_in[0];
    const int* mention_entity = (const int*)d_in[1];
    const int* mention_pos    = (const int*)d_in[2];
    const int* pair_head      = (const int*)d_in[3];
    const int* pair_tail      = (const int*)d_in[4];
    const int* pair_doc       = (const int*)d_in[5];
    const int* ent_type       = (const int*)d_in[6];

    float* out       = (float*)d_out;
    f32x4* out4      = (f32x4*)out;              // P*3*D floats
    float* out_types = out + (size_t)P * 3 * D;  // P*N_TYPES floats
    float* ent       = (float*)d_ws;             // N_ENT*D floats = 6.3 MB

    lse_kernel<<<LSE_BLOCKS, 256, 0, stream>>>(
        hidden, mention_entity, mention_pos, ent);

    sweep_kernel<<<SWEEP_GRID, 256, 0, stream>>>(
        hidden, pair_head, pair_tail, pair_doc, ent_type, ent,
        out4, out_types);
}